// Round 1
// baseline (309.581 us; speedup 1.0000x reference)
//
#include <hip/hip_runtime.h>
#include <math.h>

#define BATCH   64
#define NTGT    50
#define TOTAL   10647      // 3*(13*13 + 26*26 + 52*52)
#define NC      80
#define ROWLEN  85         // 5 + NUM_CLASSES
#define BT      (BATCH * TOTAL)   // 681408
#define EPSF    1e-7f

struct Rec { float tx, ty, tw, th, wwh; int cls; };

// ---------------------------------------------------------------------------
// Kernel 1: build targets. One thread per (b, n) ground-truth box.
//   - ignore[] = 1 where any (level, anchor) IoU > 0.5 (noobj mask)
//   - slot[]   = record id (atomicMax => last target wins, matching XLA/np
//                sequential-scatter duplicate semantics: larger n overwrites)
//   - rec[]    = per-target scatter payload
// ---------------------------------------------------------------------------
__global__ __launch_bounds__(256) void build_targets_k(
    const float* __restrict__ tgt,
    int* __restrict__ slot,
    unsigned char* __restrict__ ign,
    Rec* __restrict__ rec)
{
    int i = blockIdx.x * blockDim.x + threadIdx.x;
    if (i >= BATCH * NTGT) return;

    const float* t = tgt + (size_t)i * 5;
    float c = t[0], x = t[1], y = t[2], w = t[3], h = t[4];
    if (c + x + y + w + h == 0.0f) return;   // valid = sum(targets,-1) != 0

    int b = i / NTGT;

    const float FM[3]  = {13.f, 26.f, 52.f};
    const int   OFF[3] = {0, 507, 2535};     // 0, 3*13*13, +3*26*26
    const float AW[3][3] = {{3.625f, 4.875f, 11.65625f},
                            {1.875f, 3.875f, 3.6875f},
                            {1.25f,  2.0f,   4.125f}};
    const float AH[3][3] = {{2.8125f, 6.1875f, 10.1875f},
                            {3.8125f, 2.8125f, 7.4375f},
                            {1.625f,  3.75f,   2.875f}};

    float best_all = -1.0f;   // iou > 0 always for valid boxes
    int   best_idx = 0;
    for (int m = 0; m < 3; ++m) {
        float fm = FM[m];
        float gw = w * fm, gh = h * fm;
        int gi = (int)(x * fm);
        int gj = (int)(y * fm);
        int base = OFF[m] + 3 * gi * gj;     // reference uses A*gi*gj (product)
        float bl = -1.0f; int ba = 0;
        for (int a = 0; a < 3; ++a) {
            float inter = fminf(gw, AW[m][a]) * fminf(gh, AH[m][a]);
            float uni   = gw * gh + AW[m][a] * AH[m][a] - inter;
            float iou   = inter / (uni + 1e-16f);
            if (iou > 0.5f) ign[(size_t)b * TOTAL + base + a] = 1;
            if (iou > bl) { bl = iou; ba = a; }          // first-max tie-break
        }
        if (bl > best_all) { best_all = bl; best_idx = base + ba; }
    }

    Rec r;
    r.tx = x * 416.0f; r.ty = y * 416.0f;
    r.tw = w * 416.0f; r.th = h * 416.0f;
    r.wwh = 2.0f - w * h;
    r.cls = (int)c;
    rec[i] = r;

    // last-write-wins across duplicate cells: record id is monotone in n
    atomicMax(&slot[(size_t)b * TOTAL + best_idx], i);
}

// ---------------------------------------------------------------------------
// Kernel 2: fused loss reduction over all B*TOTAL positions.
// acc[0..7] = {sum_x, sum_y, sum_w, sum_h, sum_bce_obj, sum_bce_noobj,
//              sum_cls, n_mask}
// ---------------------------------------------------------------------------
__global__ __launch_bounds__(256) void reduce_loss_k(
    const float* __restrict__ pred,
    const int* __restrict__ slot,
    const unsigned char* __restrict__ ign,
    const Rec* __restrict__ rec,
    float* __restrict__ acc)
{
    const float NEG_LOG_1ME = -logf(1.0f - EPSF);   // bce term for clipped 0

    float sx = 0.f, sy = 0.f, sw = 0.f, sh = 0.f;
    float sb1 = 0.f, sb2 = 0.f, scl = 0.f, cnt = 0.f;

    int i = blockIdx.x * blockDim.x + threadIdx.x;
    if (i < BT) {
        const float* row = pred + (size_t)i * ROWLEN;
        float conf = row[4];
        float cc = fminf(fmaxf(conf, EPSF), 1.0f - EPSF);

        // 0.5-weighted noobj bce: p = clip(conf*noobj), t = 0
        sb2 = ign[i] ? NEG_LOG_1ME : -logf(1.0f - cc);

        int s = slot[i];
        if (s >= 0) {
            Rec r = rec[s];
            float dx = (row[0] - r.tx) * r.wwh;
            float dy = (row[1] - r.ty) * r.wwh;
            float dw = (row[2] - r.tw) * r.wwh;
            float dh = (row[3] - r.th) * r.wwh;
            sx = dx * dx; sy = dy * dy; sw = dw * dw; sh = dh * dh;
            sb1 = -logf(cc);          // p = clip(conf), t = 1
            cnt = 1.0f;
            int cid = r.cls;
            #pragma unroll 4
            for (int cc2 = 0; cc2 < NC; ++cc2) {
                float p = row[5 + cc2];
                p = fminf(fmaxf(p, EPSF), 1.0f - EPSF);
                scl += (cc2 == cid) ? -logf(p) : -logf(1.0f - p);
            }
        } else {
            sb1 = NEG_LOG_1ME;        // p = clip(0) = eps, t = 0
        }
    }

    // block reduction: wave shuffle then cross-wave via LDS
    __shared__ float red[4][8];
    float v[8] = {sx, sy, sw, sh, sb1, sb2, scl, cnt};
    int lane = threadIdx.x & 63, wid = threadIdx.x >> 6;
    #pragma unroll
    for (int k = 0; k < 8; ++k) {
        float t = v[k];
        #pragma unroll
        for (int o = 32; o > 0; o >>= 1) t += __shfl_down(t, o, 64);
        if (lane == 0) red[wid][k] = t;
    }
    __syncthreads();
    if (wid == 0 && lane < 8) {
        float t = red[0][lane] + red[1][lane] + red[2][lane] + red[3][lane];
        atomicAdd(&acc[lane], t);
    }
}

__global__ void finalize_k(const float* __restrict__ acc, float* __restrict__ out)
{
    float inv = 1.0f / (float)BT;
    float nsel = fmaxf(acc[7], 1.0f);
    float loss = (acc[0] + acc[1] + acc[2] + acc[3] + acc[4] + 0.5f * acc[5]) * inv
               + acc[6] / (nsel * (float)NC);
    out[0] = loss;
}

// ---------------------------------------------------------------------------
extern "C" void kernel_launch(void* const* d_in, const int* in_sizes, int n_in,
                              void* d_out, int out_size, void* d_ws, size_t ws_size,
                              hipStream_t stream)
{
    const float* pred = (const float*)d_in[0];   // (64, 10647, 85) f32
    const float* tgt  = (const float*)d_in[1];   // (64, 50, 5)     f32
    float* out = (float*)d_out;

    char* ws = (char*)d_ws;
    float*         acc  = (float*)ws;                       // 32 B
    int*           slot = (int*)(ws + 256);                 // BT*4 = 2,725,632 B
    unsigned char* ign  = (unsigned char*)(ws + 256 + (size_t)BT * 4);  // BT B
    Rec*           rec  = (Rec*)(ws + 3407360);             // 64-aligned, 76,800 B

    hipMemsetAsync(acc, 0, 8 * sizeof(float), stream);
    hipMemsetAsync(slot, 0xFF, (size_t)BT * 4, stream);     // slot = -1
    hipMemsetAsync(ign, 0, (size_t)BT, stream);

    build_targets_k<<<(BATCH * NTGT + 255) / 256, 256, 0, stream>>>(tgt, slot, ign, rec);
    reduce_loss_k<<<(BT + 255) / 256, 256, 0, stream>>>(pred, slot, ign, rec, acc);
    finalize_k<<<1, 1, 0, stream>>>(acc, out);
}